// Round 9
// baseline (497.909 us; speedup 1.0000x reference)
//
#include <hip/hip_runtime.h>
#include <math.h>

// Problem constants: B=4, T=512, S=1024, H=768, V=50257
#define BB 4
#define TT 512
#define SS 1024
#define HH 768
#define VV 50257
#define NW 1571            // ceil(V/32) bitmap words per batch
#define NPROJ 1536         // proj blocks (6144 rows / 4 waves)
#define NROWS (BB * TT)    // 2048 logits rows

// ---------------------------------------------------------------------------
// Kernel P: blocks [0,1536) do projections; blocks [1536,1540) do per-batch
// bitmap/prefix/rank setup (rank_g only — the row kernel no longer needs the
// bitmap: it memsets the whole row and scatter-overwrites dirty positions).
// ---------------------------------------------------------------------------
__global__ __launch_bounds__(256) void prep_kernel(
    const float* __restrict__ src, const float* __restrict__ tgt,
    const float* __restrict__ W, const float* __restrict__ bptr,
    const int* __restrict__ ids,
    float* __restrict__ src_proj, float* __restrict__ tgt_proj,
    unsigned short* __restrict__ rank_g)
{
    __shared__ unsigned bm[NW];
    __shared__ unsigned pre[NW];
    __shared__ unsigned scan[256];
    const int tid = threadIdx.x;

    if (blockIdx.x < NPROJ) {
        // ---- projection role: one wave per row, 4 rows/block ----
        const int wave = tid >> 6;
        const int lane = tid & 63;
        const int row  = blockIdx.x * 4 + wave;   // 0 .. 6143

        const float* vec;
        const float* w;
        if (row < BB * SS) { vec = src + (size_t)row * HH;            w = W; }
        else               { vec = tgt + (size_t)(row - BB*SS) * HH;  w = W + HH; }
        const float4* v4 = (const float4*)vec;
        const float4* w4 = (const float4*)w;

        float acc = 0.f;
#pragma unroll
        for (int k = 0; k < 3; ++k) {
            float4 a = v4[k * 64 + lane];
            float4 b = w4[k * 64 + lane];
            acc += a.x * b.x + a.y * b.y + a.z * b.z + a.w * b.w;
        }
#pragma unroll
        for (int off = 32; off > 0; off >>= 1) acc += __shfl_down(acc, off);
        if (lane == 0) {
            if (row < BB * SS) src_proj[row] = acc;
            else               tgt_proj[row - BB * SS] = acc + bptr[0];
        }
        return;
    }

    // ---- setup role: one block per batch ----
    const int b = blockIdx.x - NPROJ;

    for (int i = tid; i < NW; i += 256) bm[i] = 0u;
    __syncthreads();
    const int* idb = ids + b * SS;
    for (int s = tid; s < SS; s += 256) {
        const int v = idb[s];
        atomicOr(&bm[v >> 5], 1u << (v & 31));
    }
    __syncthreads();

    unsigned cnt[7];
    unsigned local = 0;
    const int w0 = tid * 7;                 // 256*7 = 1792 >= 1571
#pragma unroll
    for (int k = 0; k < 7; ++k) {
        const int w = w0 + k;
        cnt[k] = local;
        local += (w < NW) ? (unsigned)__popc(bm[w]) : 0u;
    }
    scan[tid] = local;
    __syncthreads();
    for (int off = 1; off < 256; off <<= 1) {
        const unsigned mine = scan[tid];
        const unsigned add  = (tid >= off) ? scan[tid - off] : 0u;
        __syncthreads();
        scan[tid] = mine + add;
        __syncthreads();
    }
    const unsigned excl = (tid > 0) ? scan[tid - 1] : 0u;
#pragma unroll
    for (int k = 0; k < 7; ++k) {
        const int w = w0 + k;
        if (w < NW) pre[w] = excl + cnt[k];
    }
    __syncthreads();
    for (int s = tid; s < SS; s += 256) {
        const int v = idb[s];
        const unsigned w = (unsigned)v >> 5, bit = (unsigned)v & 31u;
        const unsigned r = pre[w] + (unsigned)__popc(bm[w] & ((1u << bit) - 1u));
        rank_g[b * SS + s] = (unsigned short)r;
    }
}

// ---------------------------------------------------------------------------
// Kernel B: one block per (b,t) row.
//   pass 0: vals[rank[s]] += attn[row,s] (LDS atomics) + p_gen dot.
//   pass 1: PURE UNROLLED CONSTANT FILL of the whole row — branch-free,
//           LDS-free, data register (z4) never redefined -> no vmcnt data
//           hazard, 4 independent stores in flight per wave-iteration.
//           This is the rocclr-fill store pattern (6.1 TB/s), which none of
//           the LUT-in-loop sweeps (R0/R4/R5/R6, all ~2.3 TB/s) could reach:
//           their store data was recomputed per iteration behind LDS reads
//           and a branch, capping each wave at ~1 outstanding store.
//   barrier (implicit vmcnt(0) drains pass-1 stores; vals final).
//   pass 2: scatter-overwrite the <=1024 dirty positions from LDS vals.
//           Lines are still dirty in L2 (row = 201 KB, L2-resident), so the
//           overwrite coalesces with pass 1 before writeback — no RMW.
// ---------------------------------------------------------------------------
__global__ __launch_bounds__(256) void row_kernel(
    const float* __restrict__ attn,
    const float* __restrict__ src_proj,
    const float* __restrict__ tgt_proj,
    const unsigned short* __restrict__ rank_g,
    const int* __restrict__ ids,
    float* __restrict__ out)
{
    __shared__ float vals[SS];
    __shared__ float wsum[4];

    const int row = blockIdx.x;     // 0 .. B*T-1
    const int b   = row >> 9;       // T = 512
    const int tid = threadIdx.x;

    ((float4*)vals)[tid] = make_float4(0.f, 0.f, 0.f, 0.f);
    __syncthreads();

    // ---- pass 0: vals accumulate + p_gen dot (1024 = 4*256, vectorized) ----
    const float4  a = ((const float4*)(attn + (size_t)row * SS))[tid];
    const float4  p = ((const float4*)(src_proj + b * SS))[tid];
    const ushort4 r = ((const ushort4*)(rank_g + b * SS))[tid];
    atomicAdd(&vals[r.x], a.x);
    atomicAdd(&vals[r.y], a.y);
    atomicAdd(&vals[r.z], a.z);
    atomicAdd(&vals[r.w], a.w);
    float acc = a.x * p.x + a.y * p.y + a.z * p.z + a.w * p.w;
#pragma unroll
    for (int off = 32; off > 0; off >>= 1) acc += __shfl_down(acc, off);
    if ((tid & 63) == 0) wsum[tid >> 6] = acc;

    // ---- pass 1: pure constant fill of the row (overlaps atomics above) ----
    float* lp = out + NROWS + (size_t)row * VV;
    const int h = (4 - (row & 3)) & 3;      // head floats to 16B alignment
    if (tid < h) lp[tid] = 0.f;
    float4* lp4 = (float4*)(lp + h);
    const int n4 = (VV - h) >> 2;           // aligned float4 groups
    const float4 z4 = make_float4(0.f, 0.f, 0.f, 0.f);
    int i = tid;
    for (; i + 768 < n4; i += 1024) {       // 4 independent stores in flight
        lp4[i]       = z4;
        lp4[i + 256] = z4;
        lp4[i + 512] = z4;
        lp4[i + 768] = z4;
    }
    for (; i < n4; i += 256) lp4[i] = z4;
    const int t0 = h + (n4 << 2);           // tail floats (<= 3)
    if (t0 + tid < VV) lp[t0 + tid] = 0.f;

    __syncthreads();   // vals final + wsum visible + pass-1 stores drained

    if (tid == 0) {
        const float x = wsum[0] + wsum[1] + wsum[2] + wsum[3] + tgt_proj[row];
        out[row] = 1.f / (1.f + expf(-x));
    }

    // ---- pass 2: scatter-overwrite dirty positions (values from LDS) ----
    const int*            idb = ids    + b * SS;
    const unsigned short* rb  = rank_g + b * SS;
    for (int s = tid; s < SS; s += 256)
        lp[idb[s]] = vals[rb[s]];           // duplicates: same rank -> same value
}

extern "C" void kernel_launch(void* const* d_in, const int* in_sizes, int n_in,
                              void* d_out, int out_size, void* d_ws, size_t ws_size,
                              hipStream_t stream) {
    const int*   ids  = (const int*)d_in[0];    // [B,S]
    const float* attn = (const float*)d_in[1];  // [B,T,S]
    const float* src  = (const float*)d_in[2];  // [B,S,H]
    const float* tgt  = (const float*)d_in[3];  // [B,T,H]
    const float* W    = (const float*)d_in[4];  // [2H,1]
    const float* bp   = (const float*)d_in[5];  // [1]

    float* out = (float*)d_out;                 // [B*T (p_gen) | B*T*V]

    // ws layout (all 16B-aligned)
    float*          src_proj = (float*)d_ws;                          // 4096 f
    float*          tgt_proj = src_proj + BB * SS;                    // 2048 f
    unsigned short* rank_g   = (unsigned short*)(tgt_proj + BB * TT); // B*S u16

    prep_kernel<<<NPROJ + BB, 256, 0, stream>>>(
        src, tgt, W, bp, ids, src_proj, tgt_proj, rank_g);
    row_kernel<<<NROWS, 256, 0, stream>>>(
        attn, src_proj, tgt_proj, rank_g, ids, out);
}